// Round 3
// baseline (2817.656 us; speedup 1.0000x reference)
//
#include <hip/hip_runtime.h>

// DyHuCoG: out = (E + A*E + A*(A*E)) / 3
// E: [N,32] f32, A: COO (vals f32, row i32, col i32), N=100001, nE=6400000.
//
// Strategy: bucket edges by row>>7 (128 rows/bucket) with LDS-histogram
// binning (write-merge-friendly runs), then SpMM with per-bucket LDS
// accumulators (no global atomics). Layer 2 fused with the combine.

constexpr int D = 32;
constexpr int RPB_LOG = 7;               // rows per bucket = 128
constexpr int RPB = 1 << RPB_LOG;
constexpr int MAXNB = 1024;              // max buckets supported (n <= 131072)

__global__ void zero_i32(int* __restrict__ p, int n) {
    int i = blockIdx.x * blockDim.x + threadIdx.x;
    if (i < n) p[i] = 0;
}
__global__ void zero_f32(float* __restrict__ p, int n) {
    int i = blockIdx.x * blockDim.x + threadIdx.x;
    if (i < n) p[i] = 0.0f;
}

// ---------------- 1) global bucket histogram (LDS-binned) ----------------
__global__ __launch_bounds__(256) void hist_buckets(
    const int* __restrict__ row, int* __restrict__ cnt, int nE, int NB) {
    __shared__ int h[MAXNB];
    for (int i = threadIdx.x; i < NB; i += 256) h[i] = 0;
    __syncthreads();
    for (int e = blockIdx.x * 256 + threadIdx.x; e < nE; e += gridDim.x * 256)
        atomicAdd(&h[row[e] >> RPB_LOG], 1);
    __syncthreads();
    for (int i = threadIdx.x; i < NB; i += 256)
        if (h[i]) atomicAdd(&cnt[i], h[i]);
}

// ---------------- 2) exclusive scan of bucket counts (NB <= 1024) --------
__global__ __launch_bounds__(1024) void scan_buckets(
    const int* __restrict__ cnt, int* __restrict__ bases,
    int* __restrict__ cursor, int NB, int nE) {
    __shared__ int s[MAXNB];
    int t = threadIdx.x;
    s[t] = (t < NB) ? cnt[t] : 0;
    __syncthreads();
    for (int off = 1; off < 1024; off <<= 1) {
        int v = (t >= off) ? s[t - off] : 0;
        __syncthreads();
        s[t] += v;
        __syncthreads();
    }
    if (t < NB) {
        int b = (t == 0) ? 0 : s[t - 1];
        bases[t] = b;
        cursor[t] = b;
    }
    if (t == 0) bases[NB] = nE;
}

// ---------------- 3) bin edges into bucket regions -----------------------
// Each WG owns a contiguous edge range: local LDS hist -> one global
// cursor atomicAdd per bucket -> write packed (col|rowlow<<17, val).
__global__ __launch_bounds__(256) void bin_edges(
    const int* __restrict__ row, const int* __restrict__ col,
    const float* __restrict__ vals, int* __restrict__ cursor,
    uint2* __restrict__ cv, int nE, int NB, int perWG) {
    __shared__ int h[MAXNB];
    int start = blockIdx.x * perWG;
    int end = min(nE, start + perWG);
    if (start >= end) return;                 // block-uniform
    for (int i = threadIdx.x; i < NB; i += 256) h[i] = 0;
    __syncthreads();
    for (int e = start + threadIdx.x; e < end; e += 256)
        atomicAdd(&h[row[e] >> RPB_LOG], 1);
    __syncthreads();
    for (int i = threadIdx.x; i < NB; i += 256) {
        int c = h[i];
        h[i] = c ? atomicAdd(&cursor[i], c) : 0;   // h becomes running cursor
    }
    __syncthreads();
    for (int e = start + threadIdx.x; e < end; e += 256) {
        int r = row[e];
        int b = r >> RPB_LOG;
        int pos = atomicAdd(&h[b], 1);
        uint2 p;
        p.x = (unsigned)col[e] | ((unsigned)(r & (RPB - 1)) << 17);
        p.y = __float_as_uint(vals[e]);
        cv[pos] = p;
    }
}

// ---------------- 4) SpMM with per-bucket LDS accumulator ----------------
// One WG (256 thr = 8 lane-groups) per bucket. Gather x[col] (128B
// coalesced), atomicAdd into 128x32 LDS acc. COMBINE=1 fuses
// out = (emb + x + acc)/3 (x == y1 in layer 2).
template <int COMBINE>
__global__ __launch_bounds__(256) void spmm_bucket(
    const int* __restrict__ bases, const uint2* __restrict__ cv,
    const float* __restrict__ x, const float* __restrict__ emb,
    float* __restrict__ out, int n) {
    __shared__ float acc[RPB * D];            // 16 KB
    int t = threadIdx.x;
    for (int i = t; i < RPB * D; i += 256) acc[i] = 0.0f;
    __syncthreads();
    int b = blockIdx.x;
    int s = bases[b], e_end = bases[b + 1];
    int lane = t & 31, g = t >> 5;            // 8 groups of 32 lanes
    int total = e_end - s;
    int per = (total + 7) >> 3;
    int gs = s + g * per;
    int ge = min(e_end, gs + per);
#pragma unroll 4
    for (int e = gs; e < ge; ++e) {
        uint2 p = cv[e];
        int c = (int)(p.x & 0x1FFFF);
        int rl = (int)(p.x >> 17);
        float v = __uint_as_float(p.y);
        float xv = x[(size_t)c * D + lane];
        atomicAdd(&acc[(rl << 5) + lane], v * xv);
    }
    __syncthreads();
    int r0 = b << RPB_LOG;
    for (int i = t; i < RPB * D; i += 256) {
        int r = r0 + (i >> 5);
        if (r < n) {
            size_t idx = ((size_t)r0 << 5) + (size_t)i;   // r*32 + (i&31)
            if (COMBINE)
                out[idx] = (emb[idx] + x[idx] + acc[i]) * (1.0f / 3.0f);
            else
                out[idx] = acc[i];
        }
    }
}

// ---------------- fallback (atomic path) ----------------
__global__ __launch_bounds__(256) void spmm_atomic(
    const int* __restrict__ row, const int* __restrict__ col,
    const float* __restrict__ vals, const float* __restrict__ x,
    float* __restrict__ y, int nEdges, float scale) {
    long long t = (long long)blockIdx.x * blockDim.x + threadIdx.x;
    int e = (int)(t >> 5);
    if (e >= nEdges) return;
    int d = (int)(t & 31);
    float g = vals[e] * scale * x[(long long)col[e] * D + d];
    atomicAdd(&y[(long long)row[e] * D + d], g);
}
__global__ void combine_third(const float* __restrict__ emb,
                              const float* __restrict__ y1,
                              float* __restrict__ out, int n) {
    int i = blockIdx.x * blockDim.x + threadIdx.x;
    if (i < n) out[i] = (emb[i] + y1[i]) * (1.0f / 3.0f);
}

extern "C" void kernel_launch(void* const* d_in, const int* in_sizes, int n_in,
                              void* d_out, int out_size, void* d_ws, size_t ws_size,
                              hipStream_t stream) {
    const float* emb  = (const float*)d_in[0];
    const float* vals = (const float*)d_in[1];
    const int*   row  = (const int*)d_in[2];
    const int*   col  = (const int*)d_in[3];
    float* out = (float*)d_out;

    const int nElem  = in_sizes[0];          // N * 32
    const int nEdges = in_sizes[1];
    const int n      = nElem / D;            // 100001
    const int NB     = (n + RPB - 1) >> RPB_LOG;
    const int BLK = 256;

    // workspace layout
    size_t off_cnt    = 0;                                  // NB ints
    size_t off_bases  = off_cnt + (size_t)NB * 4;           // NB+1 ints
    size_t off_cursor = off_bases + (size_t)(NB + 1) * 4;   // NB ints
    size_t off_cv     = (off_cursor + (size_t)NB * 4 + 7) & ~(size_t)7;
    size_t off_y1     = off_cv + (size_t)nEdges * 8;
    size_t need       = off_y1 + (size_t)nElem * 4;

    if (NB > MAXNB || ws_size < need) {
        // fallback: atomic-scatter path
        float* y1 = (float*)d_ws;
        zero_f32<<<(nElem + BLK - 1) / BLK, BLK, 0, stream>>>(y1, nElem);
        long long threads = (long long)nEdges * 32;
        int blocks = (int)((threads + BLK - 1) / BLK);
        spmm_atomic<<<blocks, BLK, 0, stream>>>(row, col, vals, emb, y1, nEdges, 1.0f);
        combine_third<<<(nElem + BLK - 1) / BLK, BLK, 0, stream>>>(emb, y1, out, nElem);
        spmm_atomic<<<blocks, BLK, 0, stream>>>(row, col, vals, y1, out, nEdges, 1.0f / 3.0f);
        return;
    }

    char* ws = (char*)d_ws;
    int*   cnt    = (int*)(ws + off_cnt);
    int*   bases  = (int*)(ws + off_bases);
    int*   cursor = (int*)(ws + off_cursor);
    uint2* cv     = (uint2*)(ws + off_cv);
    float* y1     = (float*)(ws + off_y1);

    // 1) bucket histogram
    zero_i32<<<(NB + BLK - 1) / BLK, BLK, 0, stream>>>(cnt, NB);
    hist_buckets<<<1024, BLK, 0, stream>>>(row, cnt, nEdges, NB);

    // 2) scan -> bases, cursor
    scan_buckets<<<1, 1024, 0, stream>>>(cnt, bases, cursor, NB, nEdges);

    // 3) bin edges into bucket regions
    const int G = 512;
    int perWG = (nEdges + G - 1) / G;
    bin_edges<<<G, BLK, 0, stream>>>(row, col, vals, cursor, cv, nEdges, NB, perWG);

    // 4) y1 = A * E
    spmm_bucket<0><<<NB, BLK, 0, stream>>>(bases, cv, emb, nullptr, y1, n);

    // 5) out = (E + y1 + A*y1)/3
    spmm_bucket<1><<<NB, BLK, 0, stream>>>(bases, cv, y1, emb, out, n);
}

// Round 4
// 472.629 us; speedup vs baseline: 5.9617x; 5.9617x over previous
//
#include <hip/hip_runtime.h>

// DyHuCoG: out = (E + A*E + A*(A*E)) / 3
// E: [N,32] f32, A: COO (vals f32, row i32, col i32), N=100001, nE=6400000.
//
// Pipeline:
//   1) histogram edges into 128-row buckets (LDS-binned)        ~15us
//   2) scan bucket counts -> bases                              ~5us
//   3) bin edges into bucket regions (write-merge friendly)     ~70us
//   4) per-bucket counting sort -> exact CSR (L2-local writes)  ~40us
//   5) y1  = A*E        gather-form SpMM, no atomics
//   6) out = (E + y1 + A*y1)/3   fused layer-2 SpMM + combine

constexpr int D = 32;
constexpr int RPB_LOG = 7;               // rows per bucket = 128
constexpr int RPB = 1 << RPB_LOG;
constexpr int MAXNB = 1024;              // supports n <= 131072 (17-bit col)

__global__ void zero_i32(int* __restrict__ p, int n) {
    int i = blockIdx.x * blockDim.x + threadIdx.x;
    if (i < n) p[i] = 0;
}
__global__ void zero_f32(float* __restrict__ p, int n) {
    int i = blockIdx.x * blockDim.x + threadIdx.x;
    if (i < n) p[i] = 0.0f;
}

// ---------------- 1) global bucket histogram (LDS-binned) ----------------
__global__ __launch_bounds__(256) void hist_buckets(
    const int* __restrict__ row, int* __restrict__ cnt, int nE, int NB) {
    __shared__ int h[MAXNB];
    for (int i = threadIdx.x; i < NB; i += 256) h[i] = 0;
    __syncthreads();
    for (int e = blockIdx.x * 256 + threadIdx.x; e < nE; e += gridDim.x * 256)
        atomicAdd(&h[row[e] >> RPB_LOG], 1);
    __syncthreads();
    for (int i = threadIdx.x; i < NB; i += 256)
        if (h[i]) atomicAdd(&cnt[i], h[i]);
}

// ---------------- 2) exclusive scan of bucket counts (NB <= 1024) --------
__global__ __launch_bounds__(1024) void scan_buckets(
    const int* __restrict__ cnt, int* __restrict__ bases,
    int* __restrict__ cursor, int NB, int nE) {
    __shared__ int s[MAXNB];
    int t = threadIdx.x;
    s[t] = (t < NB) ? cnt[t] : 0;
    __syncthreads();
    for (int off = 1; off < 1024; off <<= 1) {
        int v = (t >= off) ? s[t - off] : 0;
        __syncthreads();
        s[t] += v;
        __syncthreads();
    }
    if (t < NB) {
        int b = (t == 0) ? 0 : s[t - 1];
        bases[t] = b;
        cursor[t] = b;
    }
    if (t == 0) bases[NB] = nE;
}

// ---------------- 3) bin edges into bucket regions -----------------------
__global__ __launch_bounds__(256) void bin_edges(
    const int* __restrict__ row, const int* __restrict__ col,
    const float* __restrict__ vals, int* __restrict__ cursor,
    uint2* __restrict__ cv, int nE, int NB, int perWG) {
    __shared__ int h[MAXNB];
    int start = blockIdx.x * perWG;
    int end = min(nE, start + perWG);
    if (start >= end) return;                 // block-uniform
    for (int i = threadIdx.x; i < NB; i += 256) h[i] = 0;
    __syncthreads();
    for (int e = start + threadIdx.x; e < end; e += 256)
        atomicAdd(&h[row[e] >> RPB_LOG], 1);
    __syncthreads();
    for (int i = threadIdx.x; i < NB; i += 256) {
        int c = h[i];
        h[i] = c ? atomicAdd(&cursor[i], c) : 0;   // h becomes running cursor
    }
    __syncthreads();
    for (int e = start + threadIdx.x; e < end; e += 256) {
        int r = row[e];
        int b = r >> RPB_LOG;
        int pos = atomicAdd(&h[b], 1);
        uint2 p;
        p.x = (unsigned)col[e] | ((unsigned)(r & (RPB - 1)) << 17);
        p.y = __float_as_uint(vals[e]);
        cv[pos] = p;
    }
}

// ------------- 4) per-bucket counting sort -> exact CSR ------------------
// One WG per bucket. Bucket region (~64KB) is read twice (L2-resident);
// scattered writes stay inside the bucket's own contiguous output region.
__global__ __launch_bounds__(256) void csr_sort(
    const int* __restrict__ bases, const uint2* __restrict__ cv,
    uint2* __restrict__ cv2, int* __restrict__ rowptr, int n, int nE) {
    __shared__ int hist_s[RPB];
    __shared__ int cur_s[RPB];
    int t = threadIdx.x;
    int b = blockIdx.x;
    int s = bases[b], e = bases[b + 1];
    if (t < RPB) hist_s[t] = 0;
    __syncthreads();
    for (int i = s + t; i < e; i += 256)
        atomicAdd(&hist_s[cv[i].x >> 17], 1);
    __syncthreads();
    if (t < RPB) cur_s[t] = hist_s[t];
    __syncthreads();
    for (int off = 1; off < RPB; off <<= 1) {       // inclusive scan
        int v = 0;
        if (t < RPB && t >= off) v = cur_s[t - off];
        __syncthreads();
        if (t < RPB) cur_s[t] += v;
        __syncthreads();
    }
    int excl = 0;
    if (t < RPB) excl = (t == 0) ? 0 : cur_s[t - 1];
    __syncthreads();
    if (t < RPB) {
        cur_s[t] = excl;
        int r = (b << RPB_LOG) + t;
        if (r < n) rowptr[r] = s + excl;
    }
    if (b == 0 && t == 0) rowptr[n] = nE;
    __syncthreads();
    for (int i = s + t; i < e; i += 256) {
        uint2 p = cv[i];
        int r = (int)(p.x >> 17);
        int pos = s + atomicAdd(&cur_s[r], 1);
        uint2 q;
        q.x = p.x & 0x1FFFF;
        q.y = p.y;
        cv2[pos] = q;
    }
}

// ---------------- 5/6) gather-form SpMM ----------------
__global__ __launch_bounds__(256) void spmm_csr(
    const int* __restrict__ ptr, const uint2* __restrict__ cv,
    const float* __restrict__ x, float* __restrict__ y, int nRows) {
    int g = (blockIdx.x * 256 + threadIdx.x) >> 5;
    if (g >= nRows) return;
    int lane = threadIdx.x & 31;
    int e = ptr[g], end = ptr[g + 1];
    float acc = 0.0f;
    for (; e + 4 <= end; e += 4) {
        uint2 a = cv[e], b = cv[e + 1], c = cv[e + 2], d = cv[e + 3];
        float xa = x[(size_t)a.x * D + lane];
        float xb = x[(size_t)b.x * D + lane];
        float xc = x[(size_t)c.x * D + lane];
        float xd = x[(size_t)d.x * D + lane];
        acc += __uint_as_float(a.y) * xa;
        acc += __uint_as_float(b.y) * xb;
        acc += __uint_as_float(c.y) * xc;
        acc += __uint_as_float(d.y) * xd;
    }
    for (; e < end; ++e) {
        uint2 a = cv[e];
        acc += __uint_as_float(a.y) * x[(size_t)a.x * D + lane];
    }
    y[(size_t)g * D + lane] = acc;
}

__global__ __launch_bounds__(256) void spmm_csr_combine(
    const int* __restrict__ ptr, const uint2* __restrict__ cv,
    const float* __restrict__ y1, const float* __restrict__ emb,
    float* __restrict__ out, int nRows) {
    int g = (blockIdx.x * 256 + threadIdx.x) >> 5;
    if (g >= nRows) return;
    int lane = threadIdx.x & 31;
    int e = ptr[g], end = ptr[g + 1];
    float acc = 0.0f;
    for (; e + 4 <= end; e += 4) {
        uint2 a = cv[e], b = cv[e + 1], c = cv[e + 2], d = cv[e + 3];
        float xa = y1[(size_t)a.x * D + lane];
        float xb = y1[(size_t)b.x * D + lane];
        float xc = y1[(size_t)c.x * D + lane];
        float xd = y1[(size_t)d.x * D + lane];
        acc += __uint_as_float(a.y) * xa;
        acc += __uint_as_float(b.y) * xb;
        acc += __uint_as_float(c.y) * xc;
        acc += __uint_as_float(d.y) * xd;
    }
    for (; e < end; ++e) {
        uint2 a = cv[e];
        acc += __uint_as_float(a.y) * y1[(size_t)a.x * D + lane];
    }
    size_t idx = (size_t)g * D + lane;
    out[idx] = (emb[idx] + y1[idx] + acc) * (1.0f / 3.0f);
}

// ---------------- fallback (atomic path) ----------------
__global__ __launch_bounds__(256) void spmm_atomic(
    const int* __restrict__ row, const int* __restrict__ col,
    const float* __restrict__ vals, const float* __restrict__ x,
    float* __restrict__ y, int nEdges, float scale) {
    long long t = (long long)blockIdx.x * blockDim.x + threadIdx.x;
    int e = (int)(t >> 5);
    if (e >= nEdges) return;
    int d = (int)(t & 31);
    float g = vals[e] * scale * x[(long long)col[e] * D + d];
    atomicAdd(&y[(long long)row[e] * D + d], g);
}
__global__ void combine_third(const float* __restrict__ emb,
                              const float* __restrict__ y1,
                              float* __restrict__ out, int n) {
    int i = blockIdx.x * blockDim.x + threadIdx.x;
    if (i < n) out[i] = (emb[i] + y1[i]) * (1.0f / 3.0f);
}

extern "C" void kernel_launch(void* const* d_in, const int* in_sizes, int n_in,
                              void* d_out, int out_size, void* d_ws, size_t ws_size,
                              hipStream_t stream) {
    const float* emb  = (const float*)d_in[0];
    const float* vals = (const float*)d_in[1];
    const int*   row  = (const int*)d_in[2];
    const int*   col  = (const int*)d_in[3];
    float* out = (float*)d_out;

    const int nElem  = in_sizes[0];          // N * 32
    const int nEdges = in_sizes[1];
    const int n      = nElem / D;            // 100001
    const int NB     = (n + RPB - 1) >> RPB_LOG;
    const int BLK = 256;

    // workspace layout (y1 aliases cv, which is dead after csr_sort)
    size_t off_cnt    = 0;                                    // NB ints
    size_t off_bases  = off_cnt + (size_t)NB * 4;             // NB+1 ints
    size_t off_cursor = off_bases + (size_t)(NB + 1) * 4;     // NB ints
    size_t off_rowptr = off_cursor + (size_t)NB * 4;          // n+1 ints
    size_t off_cv     = (off_rowptr + (size_t)(n + 1) * 4 + 7) & ~(size_t)7;
    size_t off_cv2    = off_cv + (size_t)nEdges * 8;
    size_t need       = off_cv2 + (size_t)nEdges * 8;

    bool ok = (NB <= MAXNB) && (n <= 131072) && (ws_size >= need) &&
              ((size_t)nElem * 4 <= (size_t)nEdges * 8);

    if (!ok) {
        // fallback: atomic-scatter path
        float* y1 = (float*)d_ws;
        zero_f32<<<(nElem + BLK - 1) / BLK, BLK, 0, stream>>>(y1, nElem);
        long long threads = (long long)nEdges * 32;
        int blocks = (int)((threads + BLK - 1) / BLK);
        spmm_atomic<<<blocks, BLK, 0, stream>>>(row, col, vals, emb, y1, nEdges, 1.0f);
        combine_third<<<(nElem + BLK - 1) / BLK, BLK, 0, stream>>>(emb, y1, out, nElem);
        spmm_atomic<<<blocks, BLK, 0, stream>>>(row, col, vals, y1, out, nEdges, 1.0f / 3.0f);
        return;
    }

    char* ws = (char*)d_ws;
    int*   cnt    = (int*)(ws + off_cnt);
    int*   bases  = (int*)(ws + off_bases);
    int*   cursor = (int*)(ws + off_cursor);
    int*   rowptr = (int*)(ws + off_rowptr);
    uint2* cv     = (uint2*)(ws + off_cv);
    uint2* cv2    = (uint2*)(ws + off_cv2);
    float* y1     = (float*)(ws + off_cv);    // alias: cv dead after csr_sort

    // 1) bucket histogram
    zero_i32<<<(NB + BLK - 1) / BLK, BLK, 0, stream>>>(cnt, NB);
    hist_buckets<<<1024, BLK, 0, stream>>>(row, cnt, nEdges, NB);

    // 2) scan -> bases, cursor
    scan_buckets<<<1, 1024, 0, stream>>>(cnt, bases, cursor, NB, nEdges);

    // 3) bin edges into bucket regions
    const int G = 512;
    int perWG = (nEdges + G - 1) / G;
    bin_edges<<<G, BLK, 0, stream>>>(row, col, vals, cursor, cv, nEdges, NB, perWG);

    // 4) per-bucket counting sort -> exact CSR (cv2, rowptr)
    csr_sort<<<NB, BLK, 0, stream>>>(bases, cv, cv2, rowptr, n, nEdges);

    // 5) y1 = A * E
    int rowBlocks = (n * 32 + BLK - 1) / BLK;
    spmm_csr<<<rowBlocks, BLK, 0, stream>>>(rowptr, cv2, emb, y1, n);

    // 6) out = (E + y1 + A*y1)/3
    spmm_csr_combine<<<rowBlocks, BLK, 0, stream>>>(rowptr, cv2, y1, emb, out, n);
}

// Round 5
// 397.770 us; speedup vs baseline: 7.0836x; 1.1882x over previous
//
#include <hip/hip_runtime.h>

// DyHuCoG: out = (E + A*E + A*(A*E)) / 3
// E: [N,32] f32, A: COO (vals f32, row i32, col i32), N=100001, nE=6400000.
//
// Pipeline:
//   1) histogram edges into 128-row buckets (LDS-binned)
//   2) scan bucket counts -> bases
//   3) bin edges into bucket regions (1024-thr WGs, write-merge friendly)
//   4) per-bucket counting sort -> exact CSR (L2-local writes)
//   5) cast emb -> bf16 (gather operand)
//   6) y1  = A*E        gather-form SpMM (bf16 gathers, f32 accumulate)
//   7) out = (E + y1 + A*y1)/3   fused layer-2 SpMM + combine

constexpr int D = 32;
constexpr int RPB_LOG = 7;               // rows per bucket = 128
constexpr int RPB = 1 << RPB_LOG;
constexpr int MAXNB = 1024;              // supports n <= 131072 (17-bit col)

__device__ __forceinline__ unsigned short f2bf(float f) {
    unsigned u = __float_as_uint(f);
    unsigned r = (u + 0x7FFFu + ((u >> 16) & 1u)) >> 16;   // RNE
    return (unsigned short)r;
}
__device__ __forceinline__ float bf2f(unsigned short h) {
    return __uint_as_float((unsigned)h << 16);
}

__global__ void zero_i32(int* __restrict__ p, int n) {
    int i = blockIdx.x * blockDim.x + threadIdx.x;
    if (i < n) p[i] = 0;
}
__global__ void zero_f32(float* __restrict__ p, int n) {
    int i = blockIdx.x * blockDim.x + threadIdx.x;
    if (i < n) p[i] = 0.0f;
}
__global__ void cast_bf16(const float* __restrict__ in,
                          unsigned short* __restrict__ out, int n) {
    int i = blockIdx.x * blockDim.x + threadIdx.x;
    if (i < n) out[i] = f2bf(in[i]);
}

// ---------------- 1) global bucket histogram (LDS-binned) ----------------
__global__ __launch_bounds__(256) void hist_buckets(
    const int* __restrict__ row, int* __restrict__ cnt, int nE, int NB) {
    __shared__ int h[MAXNB];
    for (int i = threadIdx.x; i < NB; i += 256) h[i] = 0;
    __syncthreads();
    for (int e = blockIdx.x * 256 + threadIdx.x; e < nE; e += gridDim.x * 256)
        atomicAdd(&h[row[e] >> RPB_LOG], 1);
    __syncthreads();
    for (int i = threadIdx.x; i < NB; i += 256)
        if (h[i]) atomicAdd(&cnt[i], h[i]);
}

// ---------------- 2) exclusive scan of bucket counts (NB <= 1024) --------
__global__ __launch_bounds__(1024) void scan_buckets(
    const int* __restrict__ cnt, int* __restrict__ bases,
    int* __restrict__ cursor, int NB, int nE) {
    __shared__ int s[MAXNB];
    int t = threadIdx.x;
    s[t] = (t < NB) ? cnt[t] : 0;
    __syncthreads();
    for (int off = 1; off < 1024; off <<= 1) {
        int v = (t >= off) ? s[t - off] : 0;
        __syncthreads();
        s[t] += v;
        __syncthreads();
    }
    if (t < NB) {
        int b = (t == 0) ? 0 : s[t - 1];
        bases[t] = b;
        cursor[t] = b;
    }
    if (t == 0) bases[NB] = nE;
}

// ---------------- 3) bin edges into bucket regions (1024-thr WGs) --------
__global__ __launch_bounds__(1024) void bin_edges(
    const int* __restrict__ row, const int* __restrict__ col,
    const float* __restrict__ vals, int* __restrict__ cursor,
    uint2* __restrict__ cv, int nE, int NB, int perWG) {
    __shared__ int h[MAXNB];
    int start = blockIdx.x * perWG;
    int end = min(nE, start + perWG);
    if (start >= end) return;                 // block-uniform
    for (int i = threadIdx.x; i < NB; i += 1024) h[i] = 0;
    __syncthreads();
    for (int e = start + threadIdx.x; e < end; e += 1024)
        atomicAdd(&h[row[e] >> RPB_LOG], 1);
    __syncthreads();
    for (int i = threadIdx.x; i < NB; i += 1024) {
        int c = h[i];
        h[i] = c ? atomicAdd(&cursor[i], c) : 0;   // h becomes running cursor
    }
    __syncthreads();
    for (int e = start + threadIdx.x; e < end; e += 1024) {
        int r = row[e];
        int b = r >> RPB_LOG;
        int pos = atomicAdd(&h[b], 1);
        uint2 p;
        p.x = (unsigned)col[e] | ((unsigned)(r & (RPB - 1)) << 17);
        p.y = __float_as_uint(vals[e]);
        cv[pos] = p;
    }
}

// ------------- 4) per-bucket counting sort -> exact CSR ------------------
__global__ __launch_bounds__(512) void csr_sort(
    const int* __restrict__ bases, const uint2* __restrict__ cv,
    uint2* __restrict__ cv2, int* __restrict__ rowptr, int n, int nE) {
    __shared__ int hist_s[RPB];
    __shared__ int cur_s[RPB];
    int t = threadIdx.x;
    int b = blockIdx.x;
    int s = bases[b], e = bases[b + 1];
    if (t < RPB) hist_s[t] = 0;
    __syncthreads();
    for (int i = s + t; i < e; i += 512)
        atomicAdd(&hist_s[cv[i].x >> 17], 1);
    __syncthreads();
    if (t < RPB) cur_s[t] = hist_s[t];
    __syncthreads();
    for (int off = 1; off < RPB; off <<= 1) {       // inclusive scan
        int v = 0;
        if (t < RPB && t >= off) v = cur_s[t - off];
        __syncthreads();
        if (t < RPB) cur_s[t] += v;
        __syncthreads();
    }
    int excl = 0;
    if (t < RPB) excl = (t == 0) ? 0 : cur_s[t - 1];
    __syncthreads();
    if (t < RPB) {
        cur_s[t] = excl;
        int r = (b << RPB_LOG) + t;
        if (r < n) rowptr[r] = s + excl;
    }
    if (b == 0 && t == 0) rowptr[n] = nE;
    __syncthreads();
    for (int i = s + t; i < e; i += 512) {
        uint2 p = cv[i];
        int r = (int)(p.x >> 17);
        int pos = s + atomicAdd(&cur_s[r], 1);
        uint2 q;
        q.x = p.x & 0x1FFFF;
        q.y = p.y;
        cv2[pos] = q;
    }
}

// ---------------- 6) layer-1 SpMM: y1 = A*E (bf16 gathers) ----------------
__global__ __launch_bounds__(256) void spmm_csr_l1(
    const int* __restrict__ ptr, const uint2* __restrict__ cv,
    const unsigned short* __restrict__ xh, float* __restrict__ y,
    unsigned short* __restrict__ yh, int nRows) {
    int g = (blockIdx.x * 256 + threadIdx.x) >> 5;
    if (g >= nRows) return;
    int lane = threadIdx.x & 31;
    int e = ptr[g], end = ptr[g + 1];
    float acc = 0.0f;
    for (; e + 4 <= end; e += 4) {
        uint2 a = cv[e], b = cv[e + 1], c = cv[e + 2], d = cv[e + 3];
        float xa = bf2f(xh[(size_t)a.x * D + lane]);
        float xb = bf2f(xh[(size_t)b.x * D + lane]);
        float xc = bf2f(xh[(size_t)c.x * D + lane]);
        float xd = bf2f(xh[(size_t)d.x * D + lane]);
        acc += __uint_as_float(a.y) * xa;
        acc += __uint_as_float(b.y) * xb;
        acc += __uint_as_float(c.y) * xc;
        acc += __uint_as_float(d.y) * xd;
    }
    for (; e < end; ++e) {
        uint2 a = cv[e];
        acc += __uint_as_float(a.y) * bf2f(xh[(size_t)a.x * D + lane]);
    }
    size_t idx = (size_t)g * D + lane;
    y[idx] = acc;
    yh[idx] = f2bf(acc);
}

// ------- 7) layer-2 SpMM fused with combine: out=(emb+y1+A*y1)/3 ---------
__global__ __launch_bounds__(256) void spmm_csr_combine(
    const int* __restrict__ ptr, const uint2* __restrict__ cv,
    const unsigned short* __restrict__ y1h, const float* __restrict__ y1,
    const float* __restrict__ emb, float* __restrict__ out, int nRows) {
    int g = (blockIdx.x * 256 + threadIdx.x) >> 5;
    if (g >= nRows) return;
    int lane = threadIdx.x & 31;
    int e = ptr[g], end = ptr[g + 1];
    float acc = 0.0f;
    for (; e + 4 <= end; e += 4) {
        uint2 a = cv[e], b = cv[e + 1], c = cv[e + 2], d = cv[e + 3];
        float xa = bf2f(y1h[(size_t)a.x * D + lane]);
        float xb = bf2f(y1h[(size_t)b.x * D + lane]);
        float xc = bf2f(y1h[(size_t)c.x * D + lane]);
        float xd = bf2f(y1h[(size_t)d.x * D + lane]);
        acc += __uint_as_float(a.y) * xa;
        acc += __uint_as_float(b.y) * xb;
        acc += __uint_as_float(c.y) * xc;
        acc += __uint_as_float(d.y) * xd;
    }
    for (; e < end; ++e) {
        uint2 a = cv[e];
        acc += __uint_as_float(a.y) * bf2f(y1h[(size_t)a.x * D + lane]);
    }
    size_t idx = (size_t)g * D + lane;
    out[idx] = (emb[idx] + y1[idx] + acc) * (1.0f / 3.0f);
}

// ---------------- fallback (atomic path, pure f32) ----------------
__global__ __launch_bounds__(256) void spmm_atomic(
    const int* __restrict__ row, const int* __restrict__ col,
    const float* __restrict__ vals, const float* __restrict__ x,
    float* __restrict__ y, int nEdges, float scale) {
    long long t = (long long)blockIdx.x * blockDim.x + threadIdx.x;
    int e = (int)(t >> 5);
    if (e >= nEdges) return;
    int d = (int)(t & 31);
    float g = vals[e] * scale * x[(long long)col[e] * D + d];
    atomicAdd(&y[(long long)row[e] * D + d], g);
}
__global__ void combine_third(const float* __restrict__ emb,
                              const float* __restrict__ y1,
                              float* __restrict__ out, int n) {
    int i = blockIdx.x * blockDim.x + threadIdx.x;
    if (i < n) out[i] = (emb[i] + y1[i]) * (1.0f / 3.0f);
}

extern "C" void kernel_launch(void* const* d_in, const int* in_sizes, int n_in,
                              void* d_out, int out_size, void* d_ws, size_t ws_size,
                              hipStream_t stream) {
    const float* emb  = (const float*)d_in[0];
    const float* vals = (const float*)d_in[1];
    const int*   row  = (const int*)d_in[2];
    const int*   col  = (const int*)d_in[3];
    float* out = (float*)d_out;

    const int nElem  = in_sizes[0];          // N * 32
    const int nEdges = in_sizes[1];
    const int n      = nElem / D;            // 100001
    const int NB     = (n + RPB - 1) >> RPB_LOG;
    const int BLK = 256;

    // workspace layout; after csr_sort, cv region is reused for
    // y1 (f32), embh (bf16), y1h (bf16).
    size_t off_cnt    = 0;                                    // NB ints
    size_t off_bases  = off_cnt + (size_t)NB * 4;             // NB+1 ints
    size_t off_cursor = off_bases + (size_t)(NB + 1) * 4;     // NB ints
    size_t off_rowptr = off_cursor + (size_t)NB * 4;          // n+1 ints
    size_t off_cv     = (off_rowptr + (size_t)(n + 1) * 4 + 7) & ~(size_t)7;
    size_t off_cv2    = off_cv + (size_t)nEdges * 8;
    size_t need       = off_cv2 + (size_t)nEdges * 8;

    // aliases inside cv region: y1(4B*nElem) | embh(2B*nElem) | y1h(2B*nElem)
    bool aliasFit = ((size_t)nElem * 8 <= (size_t)nEdges * 8);

    bool ok = (NB <= MAXNB) && (n <= 131072) && (ws_size >= need) && aliasFit;

    if (!ok) {
        // fallback: atomic-scatter path (f32 exact-ish)
        float* y1 = (float*)d_ws;
        zero_f32<<<(nElem + BLK - 1) / BLK, BLK, 0, stream>>>(y1, nElem);
        long long threads = (long long)nEdges * 32;
        int blocks = (int)((threads + BLK - 1) / BLK);
        spmm_atomic<<<blocks, BLK, 0, stream>>>(row, col, vals, emb, y1, nEdges, 1.0f);
        combine_third<<<(nElem + BLK - 1) / BLK, BLK, 0, stream>>>(emb, y1, out, nElem);
        spmm_atomic<<<blocks, BLK, 0, stream>>>(row, col, vals, y1, out, nEdges, 1.0f / 3.0f);
        return;
    }

    char* ws = (char*)d_ws;
    int*   cnt    = (int*)(ws + off_cnt);
    int*   bases  = (int*)(ws + off_bases);
    int*   cursor = (int*)(ws + off_cursor);
    int*   rowptr = (int*)(ws + off_rowptr);
    uint2* cv     = (uint2*)(ws + off_cv);
    uint2* cv2    = (uint2*)(ws + off_cv2);
    float*          y1   = (float*)(ws + off_cv);
    unsigned short* embh = (unsigned short*)(ws + off_cv + (size_t)nElem * 4);
    unsigned short* y1h  = (unsigned short*)(ws + off_cv + (size_t)nElem * 6);

    // 1) bucket histogram
    zero_i32<<<(NB + BLK - 1) / BLK, BLK, 0, stream>>>(cnt, NB);
    hist_buckets<<<1024, BLK, 0, stream>>>(row, cnt, nEdges, NB);

    // 2) scan -> bases, cursor
    scan_buckets<<<1, 1024, 0, stream>>>(cnt, bases, cursor, NB, nEdges);

    // 3) bin edges into bucket regions
    const int G = 512;
    int perWG = (nEdges + G - 1) / G;
    bin_edges<<<G, 1024, 0, stream>>>(row, col, vals, cursor, cv, nEdges, NB, perWG);

    // 4) per-bucket counting sort -> exact CSR (cv2, rowptr); cv dead after
    csr_sort<<<NB, 512, 0, stream>>>(bases, cv, cv2, rowptr, n, nEdges);

    // 5) embh = bf16(emb)
    cast_bf16<<<(nElem + BLK - 1) / BLK, BLK, 0, stream>>>(emb, embh, nElem);

    // 6) y1 = A*E (writes f32 y1 + bf16 y1h)
    int rowBlocks = (n * 32 + BLK - 1) / BLK;
    spmm_csr_l1<<<rowBlocks, BLK, 0, stream>>>(rowptr, cv2, embh, y1, y1h, n);

    // 7) out = (E + y1 + A*y1)/3
    spmm_csr_combine<<<rowBlocks, BLK, 0, stream>>>(rowptr, cv2, y1h, y1, emb, out, n);
}